// Round 8
// baseline (798.536 us; speedup 1.0000x reference)
//
#include <hip/hip_runtime.h>
#include <math.h>

#define NROWS 2048
#define DDIM 32
#define SBLK 16               // stats blocks per array
#define SROWS (NROWS / SBLK)  // 128 rows per stats block
#define REPS 5  // diagnostic: dur = base + (REPS-1)*k_C; surfaces main kernel in rocprof

// ---------------------------------------------------------------------------
// Stage 1: coalesced per-column partial sums. 32 blocks; block b covers
// array a=b>>4, rows [blk*128, blk*128+128). part[b][0:32]=sum, [32:64]=sumsq.
// ---------------------------------------------------------------------------
__global__ __launch_bounds__(256) void HybridKernel_stats_partial(
    const float* __restrict__ x, const float* __restrict__ y,
    float* __restrict__ part) {
  const int b = blockIdx.x;
  const int a = b >> 4;
  const int blk = b & (SBLK - 1);
  const float* in = a ? y : x;
  const int t = threadIdx.x;
  const int col = t & 31;
  const int rg = t >> 5;  // 0..7
  float s = 0.f, s2 = 0.f;
  const int r0 = blk * SROWS + rg;
#pragma unroll
  for (int i = 0; i < SROWS / 8; ++i) {
    float v = in[(r0 + i * 8) * DDIM + col];
    s += v;
    s2 = fmaf(v, v, s2);
  }
  __shared__ float ss[8][32];
  __shared__ float sq[8][32];
  ss[rg][col] = s;
  sq[rg][col] = s2;
  __syncthreads();
  if (t < 32) {
    float S = 0.f, Q = 0.f;
#pragma unroll
    for (int g = 0; g < 8; ++g) {
      S += ss[g][t];
      Q += sq[g][t];
    }
    part[b * 64 + t] = S;
    part[b * 64 + 32 + t] = Q;
  }
}

// ---------------------------------------------------------------------------
// Stage 2: identical to round 7 except the 24-phase compute core runs REPS
// times (diagnostic). Last rep's values feed the epilogue -> output identical.
// ---------------------------------------------------------------------------
__global__ __launch_bounds__(512, 2) void HybridKernel_main(
    const float* __restrict__ x, const float* __restrict__ y,
    const float* __restrict__ part, float* __restrict__ out) {
  __shared__ float4 sD[2][24 * 128];
  __shared__ float sNrm[2][128];
  __shared__ float sMu[2][32];
  __shared__ float sInv[2][32];

  const int t = threadIdx.x;
  const int i0 = blockIdx.y * 128;
  const int j0 = blockIdx.x * 128;

  // --- hoist tile global loads (independent of stats) ---
  float4 gx[2], gy[2];
#pragma unroll
  for (int rep = 0; rep < 2; ++rep) {
    const int u = t + 512 * rep;
    const int row = u >> 3;
    const int q = u & 7;
    gx[rep] = *reinterpret_cast<const float4*>(&x[(i0 + row) * DDIM + q * 4]);
    gy[rep] = *reinterpret_cast<const float4*>(&y[(j0 + row) * DDIM + q * 4]);
  }

  // --- finalize stats (mean, 1/(std+eps), ddof=1) from partials ---
  if (t < 64) {
    const int a = t >> 5;
    const int c = t & 31;
    float S = 0.f, Q = 0.f;
#pragma unroll
    for (int bb = 0; bb < SBLK; ++bb) {
      S += part[(a * SBLK + bb) * 64 + c];
      Q += part[(a * SBLK + bb) * 64 + 32 + c];
    }
    const float n = (float)NROWS;
    const float mean = S / n;
    const float var = fmaxf((Q - S * mean) / (n - 1.f), 0.f);
    sMu[a][c] = mean;
    sInv[a][c] = 1.f / (sqrtf(var) + 1e-8f);
  }
  __syncthreads();

  // --- staging: 1024 (row,quad) units per side, 2 reps over 512 threads ---
#pragma unroll
  for (int rep = 0; rep < 2; ++rep) {
    const int u = t + 512 * rep;
    const int row = u >> 3;
    const int q = u & 7;
#pragma unroll
    for (int side = 0; side < 2; ++side) {
      const float4 g = side ? gy[rep] : gx[rep];
      const float sc = side ? 1.0f : 0.5f;
      const float gv[4] = {g.x, g.y, g.z, g.w};
      float xn[4], hc[4], hs[4];
      float nrm = 0.f;
#pragma unroll
      for (int k = 0; k < 4; ++k) {
        const int d = q * 4 + k;
        xn[k] = (gv[k] - sMu[side][d]) * sInv[side][d];
        nrm = fmaf(xn[k], xn[k], nrm);
        float sn, cs;
        __sincosf(gv[k], &sn, &cs);
        hc[k] = sc * cs;
        hs[k] = sc * sn;
      }
      sD[side][(16 + q) * 128 + (row ^ q)] =
          make_float4(xn[0], xn[1], xn[2], xn[3]);
      const int dp0 = 2 * q, dp1 = 2 * q + 1;
      sD[side][dp0 * 128 + (row ^ (dp0 & 7))] =
          make_float4(hc[0], hs[0], hc[1], hs[1]);
      sD[side][dp1 * 128 + (row ^ (dp1 & 7))] =
          make_float4(hc[2], hs[2], hc[3], hs[3]);
      nrm += __shfl_xor(nrm, 1);
      nrm += __shfl_xor(nrm, 2);
      nrm += __shfl_xor(nrm, 4);
      if ((t & 7) == 0) sNrm[side][row] = nrm;
    }
  }
  __syncthreads();

  // --- main compute: 8x4 outputs per thread, 24 phases, REPS reps ---
  const int tx = t & 31;
  const int ty = t >> 5;
  const float4* sD0 = &sD[0][0];
  const float4* sD1 = &sD[1][0];

  float acc[8][4];
  float qp[8][4];

#pragma unroll 1
  for (int rep5 = 0; rep5 < REPS; ++rep5) {
#pragma unroll
    for (int r = 0; r < 8; ++r)
#pragma unroll
      for (int c = 0; c < 4; ++c) {
        acc[r][c] = 0.f;
        qp[r][c] = 1.f;
      }

#pragma unroll
    for (int q = 0; q < 8; ++q) {
      // phase C: xn quad (slot 16+q)
      {
        const int S = 16 + q;
        const int sw = S & 7;
        float4 FX[8], FY[4];
#pragma unroll
        for (int i = 0; i < 8; ++i) FX[i] = sD0[S * 128 + ((ty + 16 * i) ^ sw)];
#pragma unroll
        for (int j = 0; j < 4; ++j) FY[j] = sD1[S * 128 + ((tx + 32 * j) ^ sw)];
#pragma unroll
        for (int r = 0; r < 8; ++r)
#pragma unroll
          for (int c = 0; c < 4; ++c) {
            float a = acc[r][c];
            a = fmaf(FX[r].x, FY[c].x, a);
            a = fmaf(FX[r].y, FY[c].y, a);
            a = fmaf(FX[r].z, FY[c].z, a);
            a = fmaf(FX[r].w, FY[c].w, a);
            acc[r][c] = a;
          }
      }
      // phases Q0, Q1: cos/sin pairs (slots 2q, 2q+1)
#pragma unroll
      for (int h = 0; h < 2; ++h) {
        const int S = 2 * q + h;
        const int sw = S & 7;
        float4 FX[8], FY[4];
#pragma unroll
        for (int i = 0; i < 8; ++i) FX[i] = sD0[S * 128 + ((ty + 16 * i) ^ sw)];
#pragma unroll
        for (int j = 0; j < 4; ++j) FY[j] = sD1[S * 128 + ((tx + 32 * j) ^ sw)];
#pragma unroll
        for (int r = 0; r < 8; ++r)
#pragma unroll
          for (int c = 0; c < 4; ++c) {
            const float t0 =
                fmaf(FX[r].x, FY[c].x, fmaf(FX[r].y, FY[c].y, 0.5f));
            const float t1 =
                fmaf(FX[r].z, FY[c].z, fmaf(FX[r].w, FY[c].w, 0.5f));
            qp[r][c] *= t0 * t1;
          }
      }
    }
    // keep each rep's result live so repeats can't be collapsed
    asm volatile("" : "+v"(acc[0][0]), "+v"(qp[0][0]));
    __builtin_amdgcn_sched_barrier(0);
  }

  // --- epilogue ---
  float nx[8], ny[4];
#pragma unroll
  for (int r = 0; r < 8; ++r) nx[r] = sNrm[0][ty + 16 * r];
#pragma unroll
  for (int c = 0; c < 4; ++c) ny[c] = sNrm[1][tx + 32 * c];

#pragma unroll
  for (int r = 0; r < 8; ++r) {
    const int row = i0 + ty + 16 * r;
    float* o = out + (size_t)row * NROWS + j0;
#pragma unroll
    for (int c = 0; c < 4; ++c) {
      const float cl = __expf(2.f * acc[r][c] - nx[r] - ny[c]);
      o[tx + 32 * c] = 0.5f * (cl + qp[r][c]);
    }
  }
}

extern "C" void kernel_launch(void* const* d_in, const int* in_sizes, int n_in,
                              void* d_out, int out_size, void* d_ws,
                              size_t ws_size, hipStream_t stream) {
  const float* x = (const float*)d_in[0];
  const float* y = (const float*)d_in[1];
  float* part = (float*)d_ws;  // 2*SBLK*64 = 2048 floats
  float* out = (float*)d_out;

  HybridKernel_stats_partial<<<2 * SBLK, 256, 0, stream>>>(x, y, part);
  dim3 grid(NROWS / 128, NROWS / 128);
  HybridKernel_main<<<grid, 512, 0, stream>>>(x, y, part, out);
}

// Round 9
// 29.727 us; speedup vs baseline: 26.8624x; 26.8624x over previous
//
#include <hip/hip_runtime.h>
#include <math.h>

#define NROWS 2048
#define DDIM 32
#define SBLK 32               // stats blocks per array
#define SROWS (NROWS / SBLK)  // 64 rows per stats block

// ---------------------------------------------------------------------------
// Stage 1: per-column partial sums. 64 blocks; block b covers array a=b>>5,
// rows [blk*64, blk*64+64). 8 independent loads/thread (latency-friendly).
// part[b][0:32]=sum, [32:64]=sumsq.
// ---------------------------------------------------------------------------
__global__ __launch_bounds__(256) void HybridKernel_stats_partial(
    const float* __restrict__ x, const float* __restrict__ y,
    float* __restrict__ part) {
  const int b = blockIdx.x;
  const int a = b >> 5;
  const int blk = b & (SBLK - 1);
  const float* in = a ? y : x;
  const int t = threadIdx.x;
  const int col = t & 31;
  const int rg = t >> 5;  // 0..7
  const int r0 = blk * SROWS + rg;
  float v[8];
#pragma unroll
  for (int k = 0; k < 8; ++k) v[k] = in[(r0 + 8 * k) * DDIM + col];
  float s = 0.f, s2 = 0.f;
#pragma unroll
  for (int k = 0; k < 8; ++k) {
    s += v[k];
    s2 = fmaf(v[k], v[k], s2);
  }
  __shared__ float ss[8][32];
  __shared__ float sq[8][32];
  ss[rg][col] = s;
  sq[rg][col] = s2;
  __syncthreads();
  if (t < 32) {
    float S = 0.f, Q = 0.f;
#pragma unroll
    for (int g = 0; g < 8; ++g) {
      S += ss[g][t];
      Q += sq[g][t];
    }
    part[b * 64 + t] = S;
    part[b * 64 + 32 + t] = Q;
  }
}

// ---------------------------------------------------------------------------
// Stage 2: 128x128 tile per 512-thread block (2 waves/SIMD). Micro-tile 8x4.
// LDS slot array sD[side][s*128 + (idx ^ (s&7))], 24 slots per side:
//   s = 0..15 : cos/sin d-pair dp=s -> float4 (hc0,hs0,hc1,hs1), d = 2s,2s+1
//   s = 16..23: xn quad q=s-16     -> float4 xn[4q..4q+3]
// Core: 8 quad-fused phases; each issues all 36 ds_read_b128 (ordered
// C,Q0,Q1) then computes 3 nests, so C-FMAs overlap Q-loads in flight.
// classical = exp(2*dot - nx - ny); quantum term = 0.5 + hcx*cy + hsx*sy.
// ---------------------------------------------------------------------------
__global__ __launch_bounds__(512, 2) void HybridKernel_main(
    const float* __restrict__ x, const float* __restrict__ y,
    const float* __restrict__ part, float* __restrict__ out) {
  __shared__ float4 sD[2][24 * 128];
  __shared__ float sNrm[2][128];
  __shared__ float sMu[2][32];
  __shared__ float sInv[2][32];

  const int t = threadIdx.x;
  const int i0 = blockIdx.y * 128;
  const int j0 = blockIdx.x * 128;

  // --- hoist tile global loads (independent of stats) ---
  float4 gx[2], gy[2];
#pragma unroll
  for (int rep = 0; rep < 2; ++rep) {
    const int u = t + 512 * rep;
    const int row = u >> 3;
    const int q = u & 7;
    gx[rep] = *reinterpret_cast<const float4*>(&x[(i0 + row) * DDIM + q * 4]);
    gy[rep] = *reinterpret_cast<const float4*>(&y[(j0 + row) * DDIM + q * 4]);
  }

  // --- finalize stats: all 512 threads; (array, col) served by 8 lanes ---
  {
    const int a = t >> 8;         // 0..1
    const int col = (t >> 3) & 31;
    const int g = t & 7;
    float S = 0.f, Q = 0.f;
#pragma unroll
    for (int m = 0; m < 4; ++m) {
      const int bb = a * SBLK + g * 4 + m;
      S += part[bb * 64 + col];
      Q += part[bb * 64 + 32 + col];
    }
    S += __shfl_xor(S, 1);
    S += __shfl_xor(S, 2);
    S += __shfl_xor(S, 4);
    Q += __shfl_xor(Q, 1);
    Q += __shfl_xor(Q, 2);
    Q += __shfl_xor(Q, 4);
    if (g == 0) {
      const float n = (float)NROWS;
      const float mean = S / n;
      const float var = fmaxf((Q - S * mean) / (n - 1.f), 0.f);
      sMu[a][col] = mean;
      sInv[a][col] = 1.f / (sqrtf(var) + 1e-8f);
    }
  }
  __syncthreads();

  // --- staging: 1024 (row,quad) units per side, 2 reps over 512 threads ---
#pragma unroll
  for (int rep = 0; rep < 2; ++rep) {
    const int u = t + 512 * rep;
    const int row = u >> 3;
    const int q = u & 7;
#pragma unroll
    for (int side = 0; side < 2; ++side) {
      const float4 g = side ? gy[rep] : gx[rep];
      const float sc = side ? 1.0f : 0.5f;
      const float gv[4] = {g.x, g.y, g.z, g.w};
      float xn[4], hc[4], hs[4];
      float nrm = 0.f;
#pragma unroll
      for (int k = 0; k < 4; ++k) {
        const int d = q * 4 + k;
        xn[k] = (gv[k] - sMu[side][d]) * sInv[side][d];
        nrm = fmaf(xn[k], xn[k], nrm);
        float sn, cs;
        __sincosf(gv[k], &sn, &cs);
        hc[k] = sc * cs;
        hs[k] = sc * sn;
      }
      sD[side][(16 + q) * 128 + (row ^ q)] =
          make_float4(xn[0], xn[1], xn[2], xn[3]);
      const int dp0 = 2 * q, dp1 = 2 * q + 1;
      sD[side][dp0 * 128 + (row ^ (dp0 & 7))] =
          make_float4(hc[0], hs[0], hc[1], hs[1]);
      sD[side][dp1 * 128 + (row ^ (dp1 & 7))] =
          make_float4(hc[2], hs[2], hc[3], hs[3]);
      nrm += __shfl_xor(nrm, 1);
      nrm += __shfl_xor(nrm, 2);
      nrm += __shfl_xor(nrm, 4);
      if ((t & 7) == 0) sNrm[side][row] = nrm;
    }
  }
  __syncthreads();

  // --- main compute: 8 quad-fused phases, 8x4 outputs per thread ---
  const int tx = t & 31;
  const int ty = t >> 5;
  const float4* sD0 = &sD[0][0];
  const float4* sD1 = &sD[1][0];

  float acc[8][4];
  float qp[8][4];
#pragma unroll
  for (int r = 0; r < 8; ++r)
#pragma unroll
    for (int c = 0; c < 4; ++c) {
      acc[r][c] = 0.f;
      qp[r][c] = 1.f;
    }

#pragma unroll 1
  for (int q = 0; q < 8; ++q) {
    const int sC = (16 + q) * 128;
    const int s0 = (2 * q) * 128;
    const int s1 = (2 * q + 1) * 128;
    const int swC = q;  // (16+q)&7
    const int sw0 = (2 * q) & 7;
    const int sw1 = (2 * q + 1) & 7;

    float4 FXC[8], FYC[4], FX0[8], FY0[4], FX1[8], FY1[4];
    // --- issue all 36 loads, C first so its compute can start earliest ---
#pragma unroll
    for (int i = 0; i < 8; ++i) FXC[i] = sD0[sC + ((ty + 16 * i) ^ swC)];
#pragma unroll
    for (int j = 0; j < 4; ++j) FYC[j] = sD1[sC + ((tx + 32 * j) ^ swC)];
#pragma unroll
    for (int i = 0; i < 8; ++i) FX0[i] = sD0[s0 + ((ty + 16 * i) ^ sw0)];
#pragma unroll
    for (int j = 0; j < 4; ++j) FY0[j] = sD1[s0 + ((tx + 32 * j) ^ sw0)];
#pragma unroll
    for (int i = 0; i < 8; ++i) FX1[i] = sD0[s1 + ((ty + 16 * i) ^ sw1)];
#pragma unroll
    for (int j = 0; j < 4; ++j) FY1[j] = sD1[s1 + ((tx + 32 * j) ^ sw1)];

    // --- C nest (overlaps Q loads in flight) ---
#pragma unroll
    for (int r = 0; r < 8; ++r)
#pragma unroll
      for (int c = 0; c < 4; ++c) {
        float a = acc[r][c];
        a = fmaf(FXC[r].x, FYC[c].x, a);
        a = fmaf(FXC[r].y, FYC[c].y, a);
        a = fmaf(FXC[r].z, FYC[c].z, a);
        a = fmaf(FXC[r].w, FYC[c].w, a);
        acc[r][c] = a;
      }
    // --- Q0 nest ---
#pragma unroll
    for (int r = 0; r < 8; ++r)
#pragma unroll
      for (int c = 0; c < 4; ++c) {
        const float t0 =
            fmaf(FX0[r].x, FY0[c].x, fmaf(FX0[r].y, FY0[c].y, 0.5f));
        const float t1 =
            fmaf(FX0[r].z, FY0[c].z, fmaf(FX0[r].w, FY0[c].w, 0.5f));
        qp[r][c] *= t0 * t1;
      }
    // --- Q1 nest ---
#pragma unroll
    for (int r = 0; r < 8; ++r)
#pragma unroll
      for (int c = 0; c < 4; ++c) {
        const float t0 =
            fmaf(FX1[r].x, FY1[c].x, fmaf(FX1[r].y, FY1[c].y, 0.5f));
        const float t1 =
            fmaf(FX1[r].z, FY1[c].z, fmaf(FX1[r].w, FY1[c].w, 0.5f));
        qp[r][c] *= t0 * t1;
      }
  }

  // --- epilogue ---
  float nx[8], ny[4];
#pragma unroll
  for (int r = 0; r < 8; ++r) nx[r] = sNrm[0][ty + 16 * r];
#pragma unroll
  for (int c = 0; c < 4; ++c) ny[c] = sNrm[1][tx + 32 * c];

#pragma unroll
  for (int r = 0; r < 8; ++r) {
    const int row = i0 + ty + 16 * r;
    float* o = out + (size_t)row * NROWS + j0;
#pragma unroll
    for (int c = 0; c < 4; ++c) {
      const float cl = __expf(2.f * acc[r][c] - nx[r] - ny[c]);
      o[tx + 32 * c] = 0.5f * (cl + qp[r][c]);
    }
  }
}

extern "C" void kernel_launch(void* const* d_in, const int* in_sizes, int n_in,
                              void* d_out, int out_size, void* d_ws,
                              size_t ws_size, hipStream_t stream) {
  const float* x = (const float*)d_in[0];
  const float* y = (const float*)d_in[1];
  float* part = (float*)d_ws;  // 2*SBLK*64 = 4096 floats (16 KB)
  float* out = (float*)d_out;

  HybridKernel_stats_partial<<<2 * SBLK, 256, 0, stream>>>(x, y, part);
  dim3 grid(NROWS / 128, NROWS / 128);
  HybridKernel_main<<<grid, 512, 0, stream>>>(x, y, part, out);
}